// Round 4
// baseline (866.953 us; speedup 1.0000x reference)
//
#include <hip/hip_runtime.h>
#include <cstdint>
#include <cstddef>

typedef short bf16x8 __attribute__((ext_vector_type(8)));
typedef float f32x4 __attribute__((ext_vector_type(4)));

__device__ __forceinline__ unsigned short f2bf(float f) {
  union { float f; unsigned u; } v; v.f = f;
  unsigned r = v.u + 0x7fffu + ((v.u >> 16) & 1u);
  return (unsigned short)(r >> 16);
}

// async global->LDS 16B per lane; LDS dest = wave-uniform base + lane*16
#define GLOAD_LDS16(gp, lp)                                            \
  __builtin_amdgcn_global_load_lds(                                    \
      (const __attribute__((address_space(1))) void*)(const void*)(gp),\
      (__attribute__((address_space(3))) void*)(void*)(lp), 16, 0, 0)

// ---------------- cast w1 fp32 -> bf16 ----------------
__global__ __launch_bounds__(256) void cast1(const float* __restrict__ w1,
                                             unsigned short* __restrict__ W1b) {
  int i = blockIdx.x * 256 + threadIdx.x;     // < 294912 float4 chunks
  float4 v = ((const float4*)w1)[i];
  ushort4 o;
  o.x = f2bf(v.x); o.y = f2bf(v.y); o.z = f2bf(v.z); o.w = f2bf(v.w);
  ((ushort4*)W1b)[i] = o;
}

// ---------------- im2col for conv1 (LDS-staged, coalesced both sides) -------
// grid: (ci_chunk=8, oh=14, n=64); block 256.
__global__ __launch_bounds__(256) void im2col1(const float* __restrict__ x,
                                               unsigned short* __restrict__ A1) {
  __shared__ float buf[64 * 126];   // 32,256 B
  int t = threadIdx.x;
  int cc = blockIdx.x, oh = blockIdx.y, n = blockIdx.z;
  int ci0 = cc * 64;
  int ih0 = oh * 3 - 1;
  for (int rowid = t; rowid < 192; rowid += 256) {
    int c = rowid / 3, r = rowid - c * 3;
    buf[c * 126 + r * 42 + 0] = 0.f;
    buf[c * 126 + r * 42 + 41] = 0.f;
  }
  for (int idx = t; idx < 1920; idx += 256) {
    int row = idx / 10, ch = idx - row * 10;
    int c = row / 3, r = row - c * 3;
    int ih = ih0 + r;
    float4 v = make_float4(0.f, 0.f, 0.f, 0.f);
    if ((unsigned)ih < 40u)
      v = *(const float4*)(x + (((size_t)n * 512 + ci0 + c) * 40 + ih) * 40 + ch * 4);
    float* dst = buf + c * 126 + r * 42 + 1 + ch * 4;
    dst[0] = v.x; dst[1] = v.y; dst[2] = v.z; dst[3] = v.w;
  }
  __syncthreads();
  for (int idx = t; idx < 2016; idx += 256) {
    int ow = idx / 144, q4 = idx - ow * 144;
    int kk = q4 * 4;
    unsigned short vv[4];
#pragma unroll
    for (int j = 0; j < 4; ++j) {
      int k = kk + j;
      int c = k / 9, rr = k - c * 9;
      int kh = rr / 3, kw = rr - kh * 3;
      vv[j] = f2bf(buf[c * 126 + kh * 42 + 3 * ow + kw]);
    }
    ushort4 o; o.x = vv[0]; o.y = vv[1]; o.z = vv[2]; o.w = vv[3];
    *(ushort4*)(A1 + ((size_t)(n * 196 + oh * 14 + ow)) * 4608 + cc * 576 + kk) = o;
  }
}

// ---------------- bf16 GEMM, K-split: Cp[z] = A*B^T over k-chunk ------------
// 256 threads = 4 waves (2x2); global_load_lds staging; BM,BN multiples of 64
template <int BM, int BN>
__global__ __launch_bounds__(256) void gemm_bf16(const unsigned short* __restrict__ A,
                                                 const unsigned short* __restrict__ B,
                                                 float* __restrict__ Cp,
                                                 int M, int N, int K, int k_chunk) {
  __shared__ __align__(16) unsigned short As[BM * 32];
  __shared__ __align__(16) unsigned short Bs[BN * 32];
  constexpr int MT = BM / 32;   // m-frags per wave
  constexpr int NT = BN / 32;   // n-frags per wave
  int m0 = blockIdx.x * BM;
  int n0 = blockIdx.y * BN;
  Cp += (size_t)blockIdx.z * M * N;
  int k_begin = blockIdx.z * k_chunk;
  int t = threadIdx.x;
  int q = (t & 63) >> 4, mr = t & 15;
  int wm = ((t >> 6) & 1) * (BM / 2);
  int wn = (t >> 7) * (BN / 2);
  f32x4 acc[MT][NT] = {};

  for (int k0 = k_begin; k0 < k_begin + k_chunk; k0 += 32) {
    __syncthreads();
#pragma unroll
    for (int i = 0; i < BM / 64; ++i) {
      int c = t + i * 256;
      GLOAD_LDS16(A + (size_t)(m0 + (c >> 2)) * K + k0 + (c & 3) * 8, As + c * 8);
    }
#pragma unroll
    for (int i = 0; i < BN / 64; ++i) {
      int c = t + i * 256;
      GLOAD_LDS16(B + (size_t)(n0 + (c >> 2)) * K + k0 + (c & 3) * 8, Bs + c * 8);
    }
    __syncthreads();
    bf16x8 af[MT], bfr[NT];
#pragma unroll
    for (int s = 0; s < MT; ++s)
      af[s] = *((const bf16x8*)(As + (wm + s * 16 + mr) * 32 + q * 8));
#pragma unroll
    for (int nt = 0; nt < NT; ++nt)
      bfr[nt] = *((const bf16x8*)(Bs + (wn + nt * 16 + mr) * 32 + q * 8));
#pragma unroll
    for (int nt = 0; nt < NT; ++nt)
#pragma unroll
      for (int s = 0; s < MT; ++s)
        acc[s][nt] = __builtin_amdgcn_mfma_f32_16x16x32_bf16(af[s], bfr[nt], acc[s][nt], 0, 0, 0);
  }
  // C/D layout: row = q*4 + reg (M-dim), col = mr (N-dim)   [m89-verified]
#pragma unroll
  for (int s = 0; s < MT; ++s)
#pragma unroll
    for (int nt = 0; nt < NT; ++nt)
#pragma unroll
      for (int r = 0; r < 4; ++r)
        Cp[(size_t)(m0 + wm + s * 16 + q * 4 + r) * N + n0 + wn + nt * 16 + mr] = acc[s][nt][r];
}

// ---------------- reduce conv1 partials -> A2 (bf16, conv2-gathered) + stats
// One block per m2=(n,oh,ow) row of A2 (1600 blocks, 256 threads = ci).
// A2[m2][ci*9 + kh*3 + kw] = c1[n, 3oh-1+kh, 3ow-1+kw, ci] (0 if pad).
// The stride-3 conv2 im2col is a bijection: every C1 value used exactly once.
__global__ __launch_bounds__(256) void reduce1_scatter(const float* __restrict__ C1P,
                                                       unsigned short* __restrict__ A2,
                                                       float* __restrict__ SUM1,
                                                       float* __restrict__ SQ1) {
  __shared__ __align__(16) unsigned short row[2304];
  int m2 = blockIdx.x, t = threadIdx.x;
  int n = m2 / 25, sp = m2 - n * 25;
  int oh = sp / 5, ow = sp - oh * 5;
  float s = 0.f, s2 = 0.f;
#pragma unroll
  for (int r = 0; r < 9; ++r) {
    int kh = r / 3, kw = r - kh * 3;
    int ih = 3 * oh - 1 + kh, iw = 3 * ow - 1 + kw;   // ih,iw <= 13 always
    float v = 0.f;
    if (ih >= 0 && iw >= 0) {
      size_t off = (size_t)(n * 196 + ih * 14 + iw) * 256 + t;
      v = C1P[off] + C1P[3211264 + off];              // ks=2 partials
      s += v; s2 += v * v;
    }
    row[t * 9 + r] = f2bf(v);
  }
  atomicAdd(&SUM1[t], s);
  atomicAdd(&SQ1[t], s2);
  __syncthreads();
  uint4* dst = (uint4*)(A2 + (size_t)m2 * 2304);
  const uint4* src = (const uint4*)row;
  for (int i = t; i < 288; i += 256) dst[i] = src[i];
}

// ---------------- prep: W2' = bf16(w2 * bn1_scale[ci]); T[sp][n] = shift-fold
__global__ __launch_bounds__(256) void prep2(const float* __restrict__ w2,
                                             const float* __restrict__ g1,
                                             const float* __restrict__ b1,
                                             const float* __restrict__ SUM1,
                                             const float* __restrict__ SQ1,
                                             unsigned short* __restrict__ W2s,
                                             float* __restrict__ T) {
  int bid = blockIdx.x, t = threadIdx.x;
  if (bid < 1152) {
    int idx = bid * 256 + t;                  // < 294912
    int k2 = idx % 2304; int ci = k2 / 9;
    float mean = SUM1[ci] * (1.f / 12544.f);
    float var = SQ1[ci] * (1.f / 12544.f) - mean * mean;
    float sc = g1[ci] * rsqrtf(var + 1e-5f);
    W2s[idx] = f2bf(w2[idx] * sc);
  } else {
    int b2 = bid - 1152;                      // < 3200
    int sp = b2 >> 7, n = b2 & 127;
    int oh = sp / 5, ow = sp - oh * 5;
    float p = 0.f;
    for (int k2 = t; k2 < 2304; k2 += 256) {
      int ci = k2 / 9, r = k2 - ci * 9;
      int ih = 3 * oh - 1 + r / 3, iw = 3 * ow - 1 + r % 3;
      if (ih >= 0 && iw >= 0) {
        float mean = SUM1[ci] * (1.f / 12544.f);
        float var = SQ1[ci] * (1.f / 12544.f) - mean * mean;
        float sc = g1[ci] * rsqrtf(var + 1e-5f);
        float sh = b1[ci] - mean * sc;
        p += w2[n * 2304 + k2] * sh;
      }
    }
    __shared__ float red[256];
    red[t] = p; __syncthreads();
    for (int s = 128; s > 0; s >>= 1) {
      if (t < s) red[t] += red[t + s];
      __syncthreads();
    }
    if (t == 0) T[sp * 128 + n] = red[0];
  }
}

// ---------------- reduce conv2 partials + shift table + BN2 stats ----------
__global__ void reduce2_k(const float* __restrict__ C2P, const float* __restrict__ T,
                          float* __restrict__ C2, float* __restrict__ SUM2,
                          float* __restrict__ SQ2) {
  int c = threadIdx.x;            // 128
  int r0 = blockIdx.x * 16;       // 100 blocks
  float s = 0.f, s2 = 0.f;
  for (int r = 0; r < 16; ++r) {
    int m = r0 + r, sp = m % 25;
    size_t off = (size_t)m * 128 + c;
    float v = T[sp * 128 + c];
#pragma unroll
    for (int k = 0; k < 8; ++k) v += C2P[(size_t)k * 204800 + off];
    C2[off] = v;
    s += v; s2 += v * v;
  }
  atomicAdd(&SUM2[c], s);
  atomicAdd(&SQ2[c], s2);
}

// ---------------- MLP composition ----------------
__global__ void mlp_head(const float* w14, const float* b14,
                         const float* w13, const float* b13,
                         const float* w12, const float* b12,
                         const float* w11, const float* b11,
                         const float* w10, const float* b10,
                         const float* w9,  const float* b9,
                         const float* w8,  const float* b8,
                         const float* w7,  const float* b7,
                         float* __restrict__ r_out, float* __restrict__ c_out) {
  __shared__ float ra[256], rb[256];
  int t = threadIdx.x;
  float cs = 0.f;
  if (t < 2) ra[t] = w14[t];
  if (t == 0) cs = b14[0];
  __syncthreads();
  const float* Ws[7] = {w13, w12, w11, w10, w9, w8, w7};
  const float* Bs[7] = {b13, b12, b11, b10, b9, b8, b7};
  const int fouts[7] = {2, 4, 8, 16, 32, 64, 128};
  float* cur = ra; float* nxt = rb;
  for (int s = 0; s < 7; ++s) {
    int fo = fouts[s], fi = fo * 2;
    if (t == 0) {
      float d = 0.f;
      for (int i = 0; i < fo; ++i) d += cur[i] * Bs[s][i];
      cs += d;
    }
    if (t < fi) {
      float a = 0.f;
      const float* W = Ws[s];
      for (int i = 0; i < fo; ++i) a += cur[i] * W[i * fi + t];
      nxt[t] = a;
    }
    __syncthreads();
    float* tmp = cur; cur = nxt; nxt = tmp;
  }
  r_out[t] = cur[t];               // len 256
  if (t == 0) c_out[0] = cs;
}

__global__ void mlp_stage(const float* __restrict__ W, const float* __restrict__ bt,
                          const float* __restrict__ r_in, const float* __restrict__ c_in,
                          float* __restrict__ r_out, float* __restrict__ c_out,
                          int fin, int fout) {
  __shared__ float red[256];
  int t = threadIdx.x;
  int jl = t & 31, ig = t >> 5;
  int j = blockIdx.x * 32 + jl;
  int chunk = fout >> 3;
  int i0 = ig * chunk;
  float acc = 0.f;
  for (int i = i0; i < i0 + chunk; ++i)
    acc += r_in[i] * W[(size_t)i * fin + j];
  red[t] = acc;
  __syncthreads();
  if (ig == 0) {
    float s = 0.f;
#pragma unroll
    for (int u = 0; u < 8; ++u) s += red[u * 32 + jl];
    r_out[j] = s;
  }
  if (blockIdx.x == 0) {
    __syncthreads();
    float p = 0.f;
    for (int i = t; i < fout; i += 256) p += r_in[i] * bt[i];
    red[t] = p;
    __syncthreads();
    for (int s = 128; s > 0; s >>= 1) {
      if (t < s) red[t] += red[t + s];
      __syncthreads();
    }
    if (t == 0) c_out[0] = red[0] + c_in[0];
  }
}

// ---------------- final: BN2 (inline) + dot + sigmoid ----------------
__global__ void final_k(const float* __restrict__ C2, const float* __restrict__ SUM2,
                        const float* __restrict__ SQ2, const float* __restrict__ g2,
                        const float* __restrict__ b2, const float* __restrict__ r,
                        const float* __restrict__ c_in, float* __restrict__ out) {
  int n = blockIdx.x;       // 64
  int t = threadIdx.x;      // 256
  float acc = 0.f;
  for (int j = t; j < 3200; j += 256) {
    int c = j / 25, sp = j - c * 25;
    float mean = SUM2[c] * (1.f / 1600.f);
    float var = SQ2[c] * (1.f / 1600.f) - mean * mean;
    float sc = g2[c] / sqrtf(var + 1e-5f);
    float sh = b2[c] - mean * sc;
    float v = C2[((size_t)n * 25 + sp) * 128 + c] * sc + sh;
    acc += v * r[j];
  }
  __shared__ float red[256];
  red[t] = acc;
  __syncthreads();
  for (int s = 128; s > 0; s >>= 1) {
    if (t < s) red[t] += red[t + s];
    __syncthreads();
  }
  if (t == 0) {
    float z = red[0] + c_in[0];
    out[n] = 1.f / (1.f + expf(-z));
  }
}

// ---------------- workspace layout (bytes) ----------------
static constexpr size_t OFF_A1   = 0;              // 115,605,504
static constexpr size_t OFF_C1P  = 115605504;      // 2 x 12,845,056
static constexpr size_t OFF_A2   = 141295616;      // 7,372,800
static constexpr size_t OFF_C2P  = 148668416;      // 8 x 819,200
static constexpr size_t OFF_C2   = 155222016;      // 819,200
static constexpr size_t OFF_W1B  = 156041216;      // 2,359,296
static constexpr size_t OFF_W2S  = 158400512;      // 589,824
static constexpr size_t OFF_T    = 158990336;      // 12,800
static constexpr size_t OFF_STATS= 159003136;      // 4,096 (SUM1,SQ1,SUM2,SQ2)
static constexpr size_t OFF_RA   = 159007232;      // 13,056
static constexpr size_t OFF_RB   = 159020288;      // 13,056
static constexpr size_t OFF_CA   = 159033344;      // 128
static constexpr size_t OFF_CB   = 159033472;      // 128

extern "C" void kernel_launch(void* const* d_in, const int* in_sizes, int n_in,
                              void* d_out, int out_size, void* d_ws, size_t ws_size,
                              hipStream_t stream) {
  const float* x   = (const float*)d_in[0];
  const float* w1  = (const float*)d_in[1];
  const float* g1  = (const float*)d_in[3];
  const float* bb1 = (const float*)d_in[4];
  const float* w2  = (const float*)d_in[5];
  const float* g2  = (const float*)d_in[7];
  const float* bb2 = (const float*)d_in[8];

  char* ws = (char*)d_ws;
  unsigned short* A1  = (unsigned short*)(ws + OFF_A1);
  float*          C1P = (float*)(ws + OFF_C1P);
  unsigned short* A2  = (unsigned short*)(ws + OFF_A2);
  float*          C2P = (float*)(ws + OFF_C2P);
  float*          C2  = (float*)(ws + OFF_C2);
  unsigned short* W1b = (unsigned short*)(ws + OFF_W1B);
  unsigned short* W2s = (unsigned short*)(ws + OFF_W2S);
  float*          T   = (float*)(ws + OFF_T);
  float* SUM1 = (float*)(ws + OFF_STATS);
  float* SQ1  = (float*)(ws + OFF_STATS + 1024);
  float* SUM2 = (float*)(ws + OFF_STATS + 2048);
  float* SQ2  = (float*)(ws + OFF_STATS + 3072);
  float* RA   = (float*)(ws + OFF_RA);
  float* RB   = (float*)(ws + OFF_RB);
  float* CA   = (float*)(ws + OFF_CA);
  float* CB   = (float*)(ws + OFF_CB);

  hipMemsetAsync(ws + OFF_STATS, 0, 4096, stream);

  cast1<<<1152, 256, 0, stream>>>(w1, W1b);

  // conv1 as GEMM: 128x64 tiles, K-split 2 -> 784 blocks
  im2col1<<<dim3(8, 14, 64), 256, 0, stream>>>(x, A1);
  gemm_bf16<128, 64><<<dim3(98, 4, 2), 256, 0, stream>>>(A1, W1b, C1P, 12544, 256, 4608, 2304);

  // reduce partials -> A2 (conv2 im2col layout, bf16) + BN1 stats
  reduce1_scatter<<<1600, 256, 0, stream>>>(C1P, A2, SUM1, SQ1);

  // fold BN1 affine into conv2 weights + shift table
  prep2<<<4352, 256, 0, stream>>>(w2, g1, bb1, SUM1, SQ1, W2s, T);

  // conv2 as GEMM: 64x64 tiles, K-split 8 -> 400 blocks
  gemm_bf16<64, 64><<<dim3(25, 2, 8), 256, 0, stream>>>(A2, W2s, C2P, 1600, 128, 2304, 288);
  reduce2_k<<<100, 128, 0, stream>>>(C2P, T, C2, SUM2, SQ2);

  // MLP composition
  mlp_head<<<1, 256, 0, stream>>>(
      (const float*)d_in[31], (const float*)d_in[32],
      (const float*)d_in[29], (const float*)d_in[30],
      (const float*)d_in[27], (const float*)d_in[28],
      (const float*)d_in[25], (const float*)d_in[26],
      (const float*)d_in[23], (const float*)d_in[24],
      (const float*)d_in[21], (const float*)d_in[22],
      (const float*)d_in[19], (const float*)d_in[20],
      (const float*)d_in[17], (const float*)d_in[18],
      RA, CA);
  mlp_stage<<<16, 256, 0, stream>>>((const float*)d_in[15], (const float*)d_in[16],
                                    RA, CA, RB, CB, 512, 256);
  mlp_stage<<<32, 256, 0, stream>>>((const float*)d_in[13], (const float*)d_in[14],
                                    RB, CB, RA, CA, 1024, 512);
  mlp_stage<<<64, 256, 0, stream>>>((const float*)d_in[11], (const float*)d_in[12],
                                    RA, CA, RB, CB, 2048, 1024);
  mlp_stage<<<100, 256, 0, stream>>>((const float*)d_in[9], (const float*)d_in[10],
                                     RB, CB, RA, CA, 3200, 2048);

  final_k<<<64, 256, 0, stream>>>(C2, SUM2, SQ2, g2, bb2, RA, CA, (float*)d_out);
}

// Round 5
// 849.311 us; speedup vs baseline: 1.0208x; 1.0208x over previous
//
#include <hip/hip_runtime.h>
#include <cstdint>
#include <cstddef>

typedef short bf16x8 __attribute__((ext_vector_type(8)));
typedef float f32x4 __attribute__((ext_vector_type(4)));

__device__ __forceinline__ unsigned short f2bf(float f) {
  union { float f; unsigned u; } v; v.f = f;
  unsigned r = v.u + 0x7fffu + ((v.u >> 16) & 1u);
  return (unsigned short)(r >> 16);
}

// async global->LDS 16B per lane; LDS dest = wave-uniform base + lane*16
#define GLOAD_LDS16(gp, lp)                                            \
  __builtin_amdgcn_global_load_lds(                                    \
      (const __attribute__((address_space(1))) void*)(const void*)(gp),\
      (__attribute__((address_space(3))) void*)(void*)(lp), 16, 0, 0)

// ---------------- cast+reorder w1 -> W1r[co][(kh*3+kw)*512+ci] bf16 --------
__global__ __launch_bounds__(256) void cast1(const float* __restrict__ w1,
                                             unsigned short* __restrict__ W1r) {
  int idx = blockIdx.x * 256 + threadIdx.x;   // < 131072 : co*512+ci
  int co = idx >> 9, ci = idx & 511;
  const float* src = w1 + (size_t)idx * 9;
#pragma unroll
  for (int r = 0; r < 9; ++r)
    W1r[(size_t)co * 4608 + r * 512 + ci] = f2bf(src[r]);
}

// ---------------- transpose x (NCHW fp32) -> xT[img][ih+1][iw+1][ci] bf16 --
// zero halo at ih'=0/41, iw'=0/41. grid (cc=8, ihp=42, img=64), block 256.
__global__ __launch_bounds__(256) void transpose_x(const float* __restrict__ x,
                                                   unsigned short* __restrict__ xT) {
  __shared__ float lds[64 * 41];
  int t = threadIdx.x;
  int cc = blockIdx.x, ihp = blockIdx.y, img = blockIdx.z;
  int ih = ihp - 1;
  bool rowvalid = (unsigned)ih < 40u;
  if (rowvalid) {
    for (int idx = t; idx < 640; idx += 256) {   // 64 ci x 10 float4
      int row = idx / 10, q = idx - row * 10;
      float4 v = *(const float4*)(x + (((size_t)img * 512 + cc * 64 + row) * 40 + ih) * 40 + q * 4);
      float* d = lds + row * 41 + q * 4;
      d[0] = v.x; d[1] = v.y; d[2] = v.z; d[3] = v.w;
    }
  }
  __syncthreads();
  for (int idx = t; idx < 672; idx += 256) {     // 42 iwp x 16 ushort4
    int iwp = idx >> 4, u = idx & 15;
    int iw = iwp - 1;
    bool ok = rowvalid && (unsigned)iw < 40u;
    ushort4 o;
    unsigned short vv[4];
#pragma unroll
    for (int j = 0; j < 4; ++j)
      vv[j] = ok ? f2bf(lds[(u * 4 + j) * 41 + iw]) : (unsigned short)0;
    o.x = vv[0]; o.y = vv[1]; o.z = vv[2]; o.w = vv[3];
    *(ushort4*)(xT + (((size_t)img * 42 + ihp) * 42 + iwp) * 512 + cc * 64 + u * 4) = o;
  }
}

// ---------------- fused conv1 GEMM ------------------------------------------
// C[m][co] = sum_k' xT-row(m)[k'] * W1r[co][k'], k' = (kh*3+kw)*512+ci.
// Epilogue: BN1 sum/sumsq atomics + scatter C directly as A2 (conv2 im2col,
// k2' = (kh2*3+kw2)*256 + co). grid (196, 4), block 256 = 4 waves (2x2).
__global__ __launch_bounds__(256) void gemm1_fused(const unsigned short* __restrict__ xT,
                                                   const unsigned short* __restrict__ W1r,
                                                   unsigned short* __restrict__ A2,
                                                   float* __restrict__ SUM1,
                                                   float* __restrict__ SQ1) {
  __shared__ __align__(16) unsigned short As[64 * 32];
  __shared__ __align__(16) unsigned short Bs[64 * 32];
  int t = threadIdx.x;
  int m0 = blockIdx.x * 64;
  int n0 = blockIdx.y * 64;
  // A staging base: row = m0 + (t>>2); 16B piece (t&3)
  int arow = m0 + (t >> 2);
  int img_s = arow / 196, sp_s = arow - img_s * 196;
  int oh_s = sp_s / 14, ow_s = sp_s - oh_s * 14;
  const unsigned short* Abase =
      xT + (((size_t)img_s * 42 + 3 * oh_s) * 42 + 3 * ow_s) * 512 + (t & 3) * 8;
  const unsigned short* Bbase = W1r + (size_t)(n0 + (t >> 2)) * 4608 + (t & 3) * 8;
  int q = (t & 63) >> 4, mr = t & 15;
  int wm = ((t >> 6) & 1) * 32;
  int wn = (t >> 7) * 32;
  f32x4 acc[2][2] = {};

  for (int kc = 0; kc < 144; ++kc) {
    int r = kc >> 4;
    int kh = (r >= 6) ? 2 : (r >= 3 ? 1 : 0);
    int kw = r - 3 * kh;
    int aoff = (kh * 42 + kw) * 512 + ((kc & 15) << 5);
    __syncthreads();
    GLOAD_LDS16(Abase + aoff, As + t * 8);
    GLOAD_LDS16(Bbase + kc * 32, Bs + t * 8);
    __syncthreads();
    bf16x8 af[2], bfr[2];
#pragma unroll
    for (int s = 0; s < 2; ++s)
      af[s] = *((const bf16x8*)(As + (wm + s * 16 + mr) * 32 + q * 8));
#pragma unroll
    for (int nt = 0; nt < 2; ++nt)
      bfr[nt] = *((const bf16x8*)(Bs + (wn + nt * 16 + mr) * 32 + q * 8));
#pragma unroll
    for (int nt = 0; nt < 2; ++nt)
#pragma unroll
      for (int s = 0; s < 2; ++s)
        acc[s][nt] = __builtin_amdgcn_mfma_f32_16x16x32_bf16(af[s], bfr[nt], acc[s][nt], 0, 0, 0);
  }

  // ---- BN1 stats: per-column (co) sum & sumsq over this block's 64 rows ----
#pragma unroll
  for (int nt = 0; nt < 2; ++nt) {
    float cs = 0.f, cq = 0.f;
#pragma unroll
    for (int s = 0; s < 2; ++s)
#pragma unroll
      for (int rr = 0; rr < 4; ++rr) {
        float v = acc[s][nt][rr];
        cs += v; cq += v * v;
      }
    cs += __shfl_xor(cs, 16, 64); cq += __shfl_xor(cq, 16, 64);
    cs += __shfl_xor(cs, 32, 64); cq += __shfl_xor(cq, 32, 64);
    if (q == 0) {
      int col = n0 + wn + nt * 16 + mr;
      atomicAdd(&SUM1[col], cs);
      atomicAdd(&SQ1[col], cq);
    }
  }

  // ---- scatter C-tile directly into A2 (bijection; pads pre-zeroed) ----
  // C/D layout: row = q*4 + rr (M), col = mr (N)   [m89-verified]
#pragma unroll
  for (int s = 0; s < 2; ++s)
#pragma unroll
    for (int rr = 0; rr < 4; ++rr) {
      int m = m0 + wm + s * 16 + q * 4 + rr;
      int img = m / 196, sp = m - img * 196;
      int oh1 = sp / 14, ow1 = sp - oh1 * 14;
      int oh2 = (oh1 + 1) / 3, kh2 = (oh1 + 1) - 3 * oh2;
      int ow2 = (ow1 + 1) / 3, kw2 = (ow1 + 1) - 3 * ow2;
      size_t dst = (size_t)(img * 25 + oh2 * 5 + ow2) * 2304 + (kh2 * 3 + kw2) * 256;
#pragma unroll
      for (int nt = 0; nt < 2; ++nt)
        A2[dst + n0 + wn + nt * 16 + mr] = f2bf(acc[s][nt][rr]);
    }
}

// ---------------- prep2: W2s[co][(kh*3+kw)*256+ci] = bf16(w2*sc1[ci]);
//                  T4[cls][co] = sum over valid taps of w2*sh1[ci] -----------
__global__ __launch_bounds__(256) void prep2(const float* __restrict__ w2,
                                             const float* __restrict__ g1,
                                             const float* __restrict__ b1,
                                             const float* __restrict__ SUM1,
                                             const float* __restrict__ SQ1,
                                             unsigned short* __restrict__ W2s,
                                             float* __restrict__ T4) {
  int bid = blockIdx.x, t = threadIdx.x;
  if (bid < 128) {
    int idx = bid * 256 + t;            // co*256+ci
    int co = idx >> 8, ci = idx & 255;
    float mean = SUM1[ci] * (1.f / 12544.f);
    float var = SQ1[ci] * (1.f / 12544.f) - mean * mean;
    float sc = g1[ci] * rsqrtf(var + 1e-5f);
    const float* src = w2 + (size_t)idx * 9;
#pragma unroll
    for (int r = 0; r < 9; ++r)
      W2s[(size_t)co * 2304 + r * 256 + ci] = f2bf(src[r] * sc);
  } else {
    int b2 = bid - 128;                 // < 512 : cls*128 + co
    int cls = b2 >> 7, co = b2 & 127;
    int ci = t;
    float mean = SUM1[ci] * (1.f / 12544.f);
    float var = SQ1[ci] * (1.f / 12544.f) - mean * mean;
    float sc = g1[ci] * rsqrtf(var + 1e-5f);
    float sh = b1[ci] - mean * sc;
    const float* src = w2 + ((size_t)co * 256 + ci) * 9;
    float p = 0.f;
#pragma unroll
    for (int r = 0; r < 9; ++r) {
      int kh = r / 3, kw = r - 3 * kh;
      bool ok = ((cls & 2) || kh > 0) && ((cls & 1) || kw > 0);
      if (ok) p += src[r];
    }
    p *= sh;
    __shared__ float red[256];
    red[t] = p; __syncthreads();
    for (int s = 128; s > 0; s >>= 1) {
      if (t < s) red[t] += red[t + s];
      __syncthreads();
    }
    if (t == 0) T4[cls * 128 + co] = red[0];
  }
}

// ---------------- bf16 GEMM, K-split (used for conv2) -----------------------
template <int BM, int BN>
__global__ __launch_bounds__(256) void gemm_bf16(const unsigned short* __restrict__ A,
                                                 const unsigned short* __restrict__ B,
                                                 float* __restrict__ Cp,
                                                 int M, int N, int K, int k_chunk) {
  __shared__ __align__(16) unsigned short As[BM * 32];
  __shared__ __align__(16) unsigned short Bs[BN * 32];
  constexpr int MT = BM / 32;
  constexpr int NT = BN / 32;
  int m0 = blockIdx.x * BM;
  int n0 = blockIdx.y * BN;
  Cp += (size_t)blockIdx.z * M * N;
  int k_begin = blockIdx.z * k_chunk;
  int t = threadIdx.x;
  int q = (t & 63) >> 4, mr = t & 15;
  int wm = ((t >> 6) & 1) * (BM / 2);
  int wn = (t >> 7) * (BN / 2);
  f32x4 acc[MT][NT] = {};

  for (int k0 = k_begin; k0 < k_begin + k_chunk; k0 += 32) {
    __syncthreads();
#pragma unroll
    for (int i = 0; i < BM / 64; ++i) {
      int c = t + i * 256;
      GLOAD_LDS16(A + (size_t)(m0 + (c >> 2)) * K + k0 + (c & 3) * 8, As + c * 8);
    }
#pragma unroll
    for (int i = 0; i < BN / 64; ++i) {
      int c = t + i * 256;
      GLOAD_LDS16(B + (size_t)(n0 + (c >> 2)) * K + k0 + (c & 3) * 8, Bs + c * 8);
    }
    __syncthreads();
    bf16x8 af[MT], bfr[NT];
#pragma unroll
    for (int s = 0; s < MT; ++s)
      af[s] = *((const bf16x8*)(As + (wm + s * 16 + mr) * 32 + q * 8));
#pragma unroll
    for (int nt = 0; nt < NT; ++nt)
      bfr[nt] = *((const bf16x8*)(Bs + (wn + nt * 16 + mr) * 32 + q * 8));
#pragma unroll
    for (int nt = 0; nt < NT; ++nt)
#pragma unroll
      for (int s = 0; s < MT; ++s)
        acc[s][nt] = __builtin_amdgcn_mfma_f32_16x16x32_bf16(af[s], bfr[nt], acc[s][nt], 0, 0, 0);
  }
#pragma unroll
  for (int s = 0; s < MT; ++s)
#pragma unroll
    for (int nt = 0; nt < NT; ++nt)
#pragma unroll
      for (int r = 0; r < 4; ++r)
        Cp[(size_t)(m0 + wm + s * 16 + q * 4 + r) * N + n0 + wn + nt * 16 + mr] = acc[s][nt][r];
}

// ---------------- reduce conv2 partials + shift table + BN2 stats ----------
__global__ void reduce2_k(const float* __restrict__ C2P, const float* __restrict__ T4,
                          float* __restrict__ C2, float* __restrict__ SUM2,
                          float* __restrict__ SQ2) {
  int c = threadIdx.x;            // 128
  int r0 = blockIdx.x * 16;       // 100 blocks
  float s = 0.f, s2 = 0.f;
  for (int r = 0; r < 16; ++r) {
    int m = r0 + r, sp = m % 25;
    int oh = sp / 5, ow = sp - oh * 5;
    int cls = ((oh > 0) ? 2 : 0) | ((ow > 0) ? 1 : 0);
    size_t off = (size_t)m * 128 + c;
    float v = T4[cls * 128 + c];
#pragma unroll
    for (int k = 0; k < 8; ++k) v += C2P[(size_t)k * 204800 + off];
    C2[off] = v;
    s += v; s2 += v * v;
  }
  atomicAdd(&SUM2[c], s);
  atomicAdd(&SQ2[c], s2);
}

// ---------------- MLP composition ----------------
__global__ void mlp_head(const float* w14, const float* b14,
                         const float* w13, const float* b13,
                         const float* w12, const float* b12,
                         const float* w11, const float* b11,
                         const float* w10, const float* b10,
                         const float* w9,  const float* b9,
                         const float* w8,  const float* b8,
                         const float* w7,  const float* b7,
                         float* __restrict__ r_out, float* __restrict__ c_out) {
  __shared__ float ra[256], rb[256];
  int t = threadIdx.x;
  float cs = 0.f;
  if (t < 2) ra[t] = w14[t];
  if (t == 0) cs = b14[0];
  __syncthreads();
  const float* Ws[7] = {w13, w12, w11, w10, w9, w8, w7};
  const float* Bs[7] = {b13, b12, b11, b10, b9, b8, b7};
  const int fouts[7] = {2, 4, 8, 16, 32, 64, 128};
  float* cur = ra; float* nxt = rb;
  for (int s = 0; s < 7; ++s) {
    int fo = fouts[s], fi = fo * 2;
    if (t == 0) {
      float d = 0.f;
      for (int i = 0; i < fo; ++i) d += cur[i] * Bs[s][i];
      cs += d;
    }
    if (t < fi) {
      float a = 0.f;
      const float* W = Ws[s];
      for (int i = 0; i < fo; ++i) a += cur[i] * W[i * fi + t];
      nxt[t] = a;
    }
    __syncthreads();
    float* tmp = cur; cur = nxt; nxt = tmp;
  }
  r_out[t] = cur[t];               // len 256
  if (t == 0) c_out[0] = cs;
}

__global__ void mlp_stage(const float* __restrict__ W, const float* __restrict__ bt,
                          const float* __restrict__ r_in, const float* __restrict__ c_in,
                          float* __restrict__ r_out, float* __restrict__ c_out,
                          int fin, int fout) {
  __shared__ float red[256];
  int t = threadIdx.x;
  int jl = t & 31, ig = t >> 5;
  int j = blockIdx.x * 32 + jl;
  int chunk = fout >> 3;
  int i0 = ig * chunk;
  float acc = 0.f;
  for (int i = i0; i < i0 + chunk; ++i)
    acc += r_in[i] * W[(size_t)i * fin + j];
  red[t] = acc;
  __syncthreads();
  if (ig == 0) {
    float s = 0.f;
#pragma unroll
    for (int u = 0; u < 8; ++u) s += red[u * 32 + jl];
    r_out[j] = s;
  }
  if (blockIdx.x == 0) {
    __syncthreads();
    float p = 0.f;
    for (int i = t; i < fout; i += 256) p += r_in[i] * bt[i];
    red[t] = p;
    __syncthreads();
    for (int s = 128; s > 0; s >>= 1) {
      if (t < s) red[t] += red[t + s];
      __syncthreads();
    }
    if (t == 0) c_out[0] = red[0] + c_in[0];
  }
}

// ---------------- final: BN2 (inline) + dot + sigmoid ----------------
__global__ void final_k(const float* __restrict__ C2, const float* __restrict__ SUM2,
                        const float* __restrict__ SQ2, const float* __restrict__ g2,
                        const float* __restrict__ b2, const float* __restrict__ r,
                        const float* __restrict__ c_in, float* __restrict__ out) {
  int n = blockIdx.x;       // 64
  int t = threadIdx.x;      // 256
  float acc = 0.f;
  for (int j = t; j < 3200; j += 256) {
    int c = j / 25, sp = j - c * 25;
    float mean = SUM2[c] * (1.f / 1600.f);
    float var = SQ2[c] * (1.f / 1600.f) - mean * mean;
    float sc = g2[c] / sqrtf(var + 1e-5f);
    float sh = b2[c] - mean * sc;
    float v = C2[((size_t)n * 25 + sp) * 128 + c] * sc + sh;
    acc += v * r[j];
  }
  __shared__ float red[256];
  red[t] = acc;
  __syncthreads();
  for (int s = 128; s > 0; s >>= 1) {
    if (t < s) red[t] += red[t + s];
    __syncthreads();
  }
  if (t == 0) {
    float z = red[0] + c_in[0];
    out[n] = 1.f / (1.f + expf(-z));
  }
}

// ---------------- workspace layout (bytes) ----------------
static constexpr size_t OFF_XT   = 0;              // 64*42*42*512*2 = 115,605,504
static constexpr size_t OFF_A2   = 115605504;      // 1600*2304*2 = 7,372,800
static constexpr size_t OFF_C2P  = 122978304;      // 8 x 819,200 = 6,553,600
static constexpr size_t OFF_C2   = 129531904;      // 819,200
static constexpr size_t OFF_W1R  = 130351104;      // 2,359,296
static constexpr size_t OFF_W2S  = 132710400;      // 589,824
static constexpr size_t OFF_T4   = 133300224;      // 2,048
static constexpr size_t OFF_STATS= 133302272;      // 4,096 (SUM1,SQ1,SUM2,SQ2)
static constexpr size_t OFF_RA   = 133306368;      // 13,056
static constexpr size_t OFF_RB   = 133319424;      // 13,056
static constexpr size_t OFF_CA   = 133332480;      // 128
static constexpr size_t OFF_CB   = 133332608;      // 128

extern "C" void kernel_launch(void* const* d_in, const int* in_sizes, int n_in,
                              void* d_out, int out_size, void* d_ws, size_t ws_size,
                              hipStream_t stream) {
  const float* x   = (const float*)d_in[0];
  const float* w1  = (const float*)d_in[1];
  const float* g1  = (const float*)d_in[3];
  const float* bb1 = (const float*)d_in[4];
  const float* w2  = (const float*)d_in[5];
  const float* g2  = (const float*)d_in[7];
  const float* bb2 = (const float*)d_in[8];

  char* ws = (char*)d_ws;
  unsigned short* xT  = (unsigned short*)(ws + OFF_XT);
  unsigned short* A2  = (unsigned short*)(ws + OFF_A2);
  float*          C2P = (float*)(ws + OFF_C2P);
  float*          C2  = (float*)(ws + OFF_C2);
  unsigned short* W1r = (unsigned short*)(ws + OFF_W1R);
  unsigned short* W2s = (unsigned short*)(ws + OFF_W2S);
  float*          T4  = (float*)(ws + OFF_T4);
  float* SUM1 = (float*)(ws + OFF_STATS);
  float* SQ1  = (float*)(ws + OFF_STATS + 1024);
  float* SUM2 = (float*)(ws + OFF_STATS + 2048);
  float* SQ2  = (float*)(ws + OFF_STATS + 3072);
  float* RA   = (float*)(ws + OFF_RA);
  float* RB   = (float*)(ws + OFF_RB);
  float* CA   = (float*)(ws + OFF_CA);
  float* CB   = (float*)(ws + OFF_CB);

  hipMemsetAsync(ws + OFF_STATS, 0, 4096, stream);
  hipMemsetAsync(A2, 0, 7372800, stream);    // pad entries never written by gemm1

  cast1<<<512, 256, 0, stream>>>(w1, W1r);
  transpose_x<<<dim3(8, 42, 64), 256, 0, stream>>>(x, xT);

  // conv1 GEMM fused: stats + direct A2 emission (no C1 anywhere)
  gemm1_fused<<<dim3(196, 4), 256, 0, stream>>>(xT, W1r, A2, SUM1, SQ1);

  // fold BN1 affine into conv2 weights + 4-class shift table
  prep2<<<640, 256, 0, stream>>>(w2, g1, bb1, SUM1, SQ1, W2s, T4);

  // conv2 as GEMM: 64x64 tiles, K-split 8 -> 400 blocks
  gemm_bf16<64, 64><<<dim3(25, 2, 8), 256, 0, stream>>>(A2, W2s, C2P, 1600, 128, 2304, 288);
  reduce2_k<<<100, 128, 0, stream>>>(C2P, T4, C2, SUM2, SQ2);

  // MLP composition
  mlp_head<<<1, 256, 0, stream>>>(
      (const float*)d_in[31], (const float*)d_in[32],
      (const float*)d_in[29], (const float*)d_in[30],
      (const float*)d_in[27], (const float*)d_in[28],
      (const float*)d_in[25], (const float*)d_in[26],
      (const float*)d_in[23], (const float*)d_in[24],
      (const float*)d_in[21], (const float*)d_in[22],
      (const float*)d_in[19], (const float*)d_in[20],
      (const float*)d_in[17], (const float*)d_in[18],
      RA, CA);
  mlp_stage<<<16, 256, 0, stream>>>((const float*)d_in[15], (const float*)d_in[16],
                                    RA, CA, RB, CB, 512, 256);
  mlp_stage<<<32, 256, 0, stream>>>((const float*)d_in[13], (const float*)d_in[14],
                                    RB, CB, RA, CA, 1024, 512);
  mlp_stage<<<64, 256, 0, stream>>>((const float*)d_in[11], (const float*)d_in[12],
                                    RA, CA, RB, CB, 2048, 1024);
  mlp_stage<<<100, 256, 0, stream>>>((const float*)d_in[9], (const float*)d_in[10],
                                     RB, CB, RA, CA, 3200, 2048);

  final_k<<<64, 256, 0, stream>>>(C2, SUM2, SQ2, g2, bb2, RA, CA, (float*)d_out);
}

// Round 6
// 832.525 us; speedup vs baseline: 1.0414x; 1.0202x over previous
//
#include <hip/hip_runtime.h>
#include <cstdint>
#include <cstddef>

typedef short bf16x8 __attribute__((ext_vector_type(8)));
typedef float f32x4 __attribute__((ext_vector_type(4)));

__device__ __forceinline__ unsigned short f2bf(float f) {
  union { float f; unsigned u; } v; v.f = f;
  unsigned r = v.u + 0x7fffu + ((v.u >> 16) & 1u);
  return (unsigned short)(r >> 16);
}

// async global->LDS 16B per lane; LDS dest = wave-uniform base + lane*16
#define GLOAD_LDS16(gp, lp)                                            \
  __builtin_amdgcn_global_load_lds(                                    \
      (const __attribute__((address_space(1))) void*)(const void*)(gp),\
      (__attribute__((address_space(3))) void*)(void*)(lp), 16, 0, 0)

// ---------------- cast+reorder w1 -> W1r[co][(kh*3+kw)*512+ci] bf16 --------
__global__ __launch_bounds__(256) void cast1(const float* __restrict__ w1,
                                             unsigned short* __restrict__ W1r) {
  int idx = blockIdx.x * 256 + threadIdx.x;   // < 131072 : co*512+ci
  int co = idx >> 9, ci = idx & 511;
  const float* src = w1 + (size_t)idx * 9;
#pragma unroll
  for (int r = 0; r < 9; ++r)
    W1r[(size_t)co * 4608 + r * 512 + ci] = f2bf(src[r]);
}

// ---------------- transpose x (NCHW fp32) -> xT[img][ih+1][iw+1][ci] bf16 --
__global__ __launch_bounds__(256) void transpose_x(const float* __restrict__ x,
                                                   unsigned short* __restrict__ xT) {
  __shared__ float lds[64 * 41];
  int t = threadIdx.x;
  int cc = blockIdx.x, ihp = blockIdx.y, img = blockIdx.z;
  int ih = ihp - 1;
  bool rowvalid = (unsigned)ih < 40u;
  if (rowvalid) {
    for (int idx = t; idx < 640; idx += 256) {   // 64 ci x 10 float4
      int row = idx / 10, q = idx - row * 10;
      float4 v = *(const float4*)(x + (((size_t)img * 512 + cc * 64 + row) * 40 + ih) * 40 + q * 4);
      float* d = lds + row * 41 + q * 4;
      d[0] = v.x; d[1] = v.y; d[2] = v.z; d[3] = v.w;
    }
  }
  __syncthreads();
  for (int idx = t; idx < 672; idx += 256) {     // 42 iwp x 16 ushort4
    int iwp = idx >> 4, u = idx & 15;
    int iw = iwp - 1;
    bool ok = rowvalid && (unsigned)iw < 40u;
    ushort4 o;
    unsigned short vv[4];
#pragma unroll
    for (int j = 0; j < 4; ++j)
      vv[j] = ok ? f2bf(lds[(u * 4 + j) * 41 + iw]) : (unsigned short)0;
    o.x = vv[0]; o.y = vv[1]; o.z = vv[2]; o.w = vv[3];
    *(ushort4*)(xT + (((size_t)img * 42 + ihp) * 42 + iwp) * 512 + cc * 64 + u * 4) = o;
  }
}

// ---------------- fused conv1 GEMM (BK=128 per barrier) ---------------------
// C[m][co] = sum_k' xT-row(m)[k'] * W1r[co][k'], k' = (kh*3+kw)*512+ci.
// LDS: 4 sub-buffers of [64][32] each (keeps 64B row stride AND wave-uniform
// glds mapping). 36 iterations, 16 MFMA / 8 glds / 16 ds_read per wave-iter.
// Epilogue: BN1 stats + scatter directly as A2 (conv2 im2col bijection).
__global__ __launch_bounds__(256) void gemm1_fused(const unsigned short* __restrict__ xT,
                                                   const unsigned short* __restrict__ W1r,
                                                   unsigned short* __restrict__ A2,
                                                   float* __restrict__ SUM1,
                                                   float* __restrict__ SQ1) {
  __shared__ __align__(16) unsigned short As[4 * 64 * 32];   // 16 KB
  __shared__ __align__(16) unsigned short Bs[4 * 64 * 32];   // 16 KB
  int t = threadIdx.x;
  int m0 = blockIdx.x * 64;
  int n0 = blockIdx.y * 64;
  // staging: row = t>>2 (one row per thread), piece = t&3; sub-buffer i = instr i
  int arow = m0 + (t >> 2);
  int img_s = arow / 196, sp_s = arow - img_s * 196;
  int oh_s = sp_s / 14, ow_s = sp_s - oh_s * 14;
  const unsigned short* Abase =
      xT + (((size_t)img_s * 42 + 3 * oh_s) * 42 + 3 * ow_s) * 512 + (t & 3) * 8;
  const unsigned short* Bbase = W1r + (size_t)(n0 + (t >> 2)) * 4608 + (t & 3) * 8;
  int q = (t & 63) >> 4, mr = t & 15;
  int wm = ((t >> 6) & 1) * 32;
  int wn = (t >> 7) * 32;
  f32x4 acc[2][2] = {};

  for (int kc = 0; kc < 36; ++kc) {
    int r = kc >> 2;                       // tap 0..8 (wave-uniform, SALU)
    int kh = (r >= 6) ? 2 : (r >= 3 ? 1 : 0);
    int kw = r - 3 * kh;
    int aoff = (kh * 42 + kw) * 512 + (kc & 3) * 128;
    int boff = kc * 128;
    __syncthreads();
#pragma unroll
    for (int i = 0; i < 4; ++i) {
      GLOAD_LDS16(Abase + aoff + i * 32, As + (i * 256 + t) * 8);
      GLOAD_LDS16(Bbase + boff + i * 32, Bs + (i * 256 + t) * 8);
    }
    __syncthreads();
#pragma unroll
    for (int ks = 0; ks < 4; ++ks) {
      bf16x8 af[2], bfr[2];
#pragma unroll
      for (int s = 0; s < 2; ++s)
        af[s] = *((const bf16x8*)(As + ks * 2048 + (wm + s * 16 + mr) * 32 + q * 8));
#pragma unroll
      for (int nt = 0; nt < 2; ++nt)
        bfr[nt] = *((const bf16x8*)(Bs + ks * 2048 + (wn + nt * 16 + mr) * 32 + q * 8));
#pragma unroll
      for (int nt = 0; nt < 2; ++nt)
#pragma unroll
        for (int s = 0; s < 2; ++s)
          acc[s][nt] = __builtin_amdgcn_mfma_f32_16x16x32_bf16(af[s], bfr[nt], acc[s][nt], 0, 0, 0);
    }
  }

  // ---- BN1 stats: per-column (co) sum & sumsq over this block's 64 rows ----
#pragma unroll
  for (int nt = 0; nt < 2; ++nt) {
    float cs = 0.f, cq = 0.f;
#pragma unroll
    for (int s = 0; s < 2; ++s)
#pragma unroll
      for (int rr = 0; rr < 4; ++rr) {
        float v = acc[s][nt][rr];
        cs += v; cq += v * v;
      }
    cs += __shfl_xor(cs, 16, 64); cq += __shfl_xor(cq, 16, 64);
    cs += __shfl_xor(cs, 32, 64); cq += __shfl_xor(cq, 32, 64);
    if (q == 0) {
      int col = n0 + wn + nt * 16 + mr;
      atomicAdd(&SUM1[col], cs);
      atomicAdd(&SQ1[col], cq);
    }
  }

  // ---- scatter C-tile directly into A2 (bijection; pads pre-zeroed) ----
  // C/D layout: row = q*4 + rr (M), col = mr (N)   [m89-verified]
#pragma unroll
  for (int s = 0; s < 2; ++s)
#pragma unroll
    for (int rr = 0; rr < 4; ++rr) {
      int m = m0 + wm + s * 16 + q * 4 + rr;
      int img = m / 196, sp = m - img * 196;
      int oh1 = sp / 14, ow1 = sp - oh1 * 14;
      int oh2 = (oh1 + 1) / 3, kh2 = (oh1 + 1) - 3 * oh2;
      int ow2 = (ow1 + 1) / 3, kw2 = (ow1 + 1) - 3 * ow2;
      size_t dst = (size_t)(img * 25 + oh2 * 5 + ow2) * 2304 + (kh2 * 3 + kw2) * 256;
#pragma unroll
      for (int nt = 0; nt < 2; ++nt)
        A2[dst + n0 + wn + nt * 16 + mr] = f2bf(acc[s][nt][rr]);
    }
}

// ---------------- prep2: W2s[co][(kh*3+kw)*256+ci] = bf16(w2*sc1[ci]);
//                  T4[cls][co] = sum over valid taps of w2*sh1[ci] -----------
__global__ __launch_bounds__(256) void prep2(const float* __restrict__ w2,
                                             const float* __restrict__ g1,
                                             const float* __restrict__ b1,
                                             const float* __restrict__ SUM1,
                                             const float* __restrict__ SQ1,
                                             unsigned short* __restrict__ W2s,
                                             float* __restrict__ T4) {
  int bid = blockIdx.x, t = threadIdx.x;
  if (bid < 128) {
    int idx = bid * 256 + t;            // co*256+ci
    int co = idx >> 8, ci = idx & 255;
    float mean = SUM1[ci] * (1.f / 12544.f);
    float var = SQ1[ci] * (1.f / 12544.f) - mean * mean;
    float sc = g1[ci] * rsqrtf(var + 1e-5f);
    const float* src = w2 + (size_t)idx * 9;
#pragma unroll
    for (int r = 0; r < 9; ++r)
      W2s[(size_t)co * 2304 + r * 256 + ci] = f2bf(src[r] * sc);
  } else {
    int b2 = bid - 128;                 // < 512 : cls*128 + co
    int cls = b2 >> 7, co = b2 & 127;
    int ci = t;
    float mean = SUM1[ci] * (1.f / 12544.f);
    float var = SQ1[ci] * (1.f / 12544.f) - mean * mean;
    float sc = g1[ci] * rsqrtf(var + 1e-5f);
    float sh = b1[ci] - mean * sc;
    const float* src = w2 + ((size_t)co * 256 + ci) * 9;
    float p = 0.f;
#pragma unroll
    for (int r = 0; r < 9; ++r) {
      int kh = r / 3, kw = r - 3 * kh;
      bool ok = ((cls & 2) || kh > 0) && ((cls & 1) || kw > 0);
      if (ok) p += src[r];
    }
    p *= sh;
    __shared__ float red[256];
    red[t] = p; __syncthreads();
    for (int s = 128; s > 0; s >>= 1) {
      if (t < s) red[t] += red[t + s];
      __syncthreads();
    }
    if (t == 0) T4[cls * 128 + co] = red[0];
  }
}

// ---------------- bf16 GEMM 64x64, K-split, BKS 32-wide sub-buffers ---------
template <int BKS>
__global__ __launch_bounds__(256) void gemm_bf16(const unsigned short* __restrict__ A,
                                                 const unsigned short* __restrict__ B,
                                                 float* __restrict__ Cp,
                                                 int M, int N, int K, int k_chunk) {
  __shared__ __align__(16) unsigned short As[BKS * 64 * 32];
  __shared__ __align__(16) unsigned short Bs[BKS * 64 * 32];
  int m0 = blockIdx.x * 64;
  int n0 = blockIdx.y * 64;
  Cp += (size_t)blockIdx.z * M * N;
  int k_begin = blockIdx.z * k_chunk;
  int t = threadIdx.x;
  const unsigned short* Abase = A + (size_t)(m0 + (t >> 2)) * K + (t & 3) * 8;
  const unsigned short* Bbase = B + (size_t)(n0 + (t >> 2)) * K + (t & 3) * 8;
  int q = (t & 63) >> 4, mr = t & 15;
  int wm = ((t >> 6) & 1) * 32;
  int wn = (t >> 7) * 32;
  f32x4 acc[2][2] = {};

  for (int k0 = k_begin; k0 < k_begin + k_chunk; k0 += 32 * BKS) {
    __syncthreads();
#pragma unroll
    for (int i = 0; i < BKS; ++i) {
      GLOAD_LDS16(Abase + k0 + i * 32, As + (i * 256 + t) * 8);
      GLOAD_LDS16(Bbase + k0 + i * 32, Bs + (i * 256 + t) * 8);
    }
    __syncthreads();
#pragma unroll
    for (int ks = 0; ks < BKS; ++ks) {
      bf16x8 af[2], bfr[2];
#pragma unroll
      for (int s = 0; s < 2; ++s)
        af[s] = *((const bf16x8*)(As + ks * 2048 + (wm + s * 16 + mr) * 32 + q * 8));
#pragma unroll
      for (int nt = 0; nt < 2; ++nt)
        bfr[nt] = *((const bf16x8*)(Bs + ks * 2048 + (wn + nt * 16 + mr) * 32 + q * 8));
#pragma unroll
      for (int nt = 0; nt < 2; ++nt)
#pragma unroll
        for (int s = 0; s < 2; ++s)
          acc[s][nt] = __builtin_amdgcn_mfma_f32_16x16x32_bf16(af[s], bfr[nt], acc[s][nt], 0, 0, 0);
    }
  }
#pragma unroll
  for (int s = 0; s < 2; ++s)
#pragma unroll
    for (int nt = 0; nt < 2; ++nt)
#pragma unroll
      for (int r = 0; r < 4; ++r)
        Cp[(size_t)(m0 + wm + s * 16 + q * 4 + r) * N + n0 + wn + nt * 16 + mr] = acc[s][nt][r];
}

// ---------------- reduce conv2 partials + shift table + BN2 stats ----------
__global__ void reduce2_k(const float* __restrict__ C2P, const float* __restrict__ T4,
                          float* __restrict__ C2, float* __restrict__ SUM2,
                          float* __restrict__ SQ2) {
  int c = threadIdx.x;            // 128
  int r0 = blockIdx.x * 16;       // 100 blocks
  float s = 0.f, s2 = 0.f;
  for (int r = 0; r < 16; ++r) {
    int m = r0 + r, sp = m % 25;
    int oh = sp / 5, ow = sp - oh * 5;
    int cls = ((oh > 0) ? 2 : 0) | ((ow > 0) ? 1 : 0);
    size_t off = (size_t)m * 128 + c;
    float v = T4[cls * 128 + c];
#pragma unroll
    for (int k = 0; k < 8; ++k) v += C2P[(size_t)k * 204800 + off];
    C2[off] = v;
    s += v; s2 += v * v;
  }
  atomicAdd(&SUM2[c], s);
  atomicAdd(&SQ2[c], s2);
}

// ---------------- MLP composition ----------------
__global__ void mlp_head(const float* w14, const float* b14,
                         const float* w13, const float* b13,
                         const float* w12, const float* b12,
                         const float* w11, const float* b11,
                         const float* w10, const float* b10,
                         const float* w9,  const float* b9,
                         const float* w8,  const float* b8,
                         const float* w7,  const float* b7,
                         float* __restrict__ r_out, float* __restrict__ c_out) {
  __shared__ float ra[256], rb[256];
  int t = threadIdx.x;
  float cs = 0.f;
  if (t < 2) ra[t] = w14[t];
  if (t == 0) cs = b14[0];
  __syncthreads();
  const float* Ws[7] = {w13, w12, w11, w10, w9, w8, w7};
  const float* Bs[7] = {b13, b12, b11, b10, b9, b8, b7};
  const int fouts[7] = {2, 4, 8, 16, 32, 64, 128};
  float* cur = ra; float* nxt = rb;
  for (int s = 0; s < 7; ++s) {
    int fo = fouts[s], fi = fo * 2;
    if (t == 0) {
      float d = 0.f;
      for (int i = 0; i < fo; ++i) d += cur[i] * Bs[s][i];
      cs += d;
    }
    if (t < fi) {
      float a = 0.f;
      const float* W = Ws[s];
      for (int i = 0; i < fo; ++i) a += cur[i] * W[i * fi + t];
      nxt[t] = a;
    }
    __syncthreads();
    float* tmp = cur; cur = nxt; nxt = tmp;
  }
  r_out[t] = cur[t];               // len 256
  if (t == 0) c_out[0] = cs;
}

__global__ void mlp_stage(const float* __restrict__ W, const float* __restrict__ bt,
                          const float* __restrict__ r_in, const float* __restrict__ c_in,
                          float* __restrict__ r_out, float* __restrict__ c_out,
                          int fin, int fout) {
  __shared__ float red[256];
  int t = threadIdx.x;
  int jl = t & 31, ig = t >> 5;
  int j = blockIdx.x * 32 + jl;
  int chunk = fout >> 3;
  int i0 = ig * chunk;
  float acc = 0.f;
  for (int i = i0; i < i0 + chunk; ++i)
    acc += r_in[i] * W[(size_t)i * fin + j];
  red[t] = acc;
  __syncthreads();
  if (ig == 0) {
    float s = 0.f;
#pragma unroll
    for (int u = 0; u < 8; ++u) s += red[u * 32 + jl];
    r_out[j] = s;
  }
  if (blockIdx.x == 0) {
    __syncthreads();
    float p = 0.f;
    for (int i = t; i < fout; i += 256) p += r_in[i] * bt[i];
    red[t] = p;
    __syncthreads();
    for (int s = 128; s > 0; s >>= 1) {
      if (t < s) red[t] += red[t + s];
      __syncthreads();
    }
    if (t == 0) c_out[0] = red[0] + c_in[0];
  }
}

// ---------------- final: BN2 (inline) + dot + sigmoid ----------------
__global__ void final_k(const float* __restrict__ C2, const float* __restrict__ SUM2,
                        const float* __restrict__ SQ2, const float* __restrict__ g2,
                        const float* __restrict__ b2, const float* __restrict__ r,
                        const float* __restrict__ c_in, float* __restrict__ out) {
  int n = blockIdx.x;       // 64
  int t = threadIdx.x;      // 256
  float acc = 0.f;
  for (int j = t; j < 3200; j += 256) {
    int c = j / 25, sp = j - c * 25;
    float mean = SUM2[c] * (1.f / 1600.f);
    float var = SQ2[c] * (1.f / 1600.f) - mean * mean;
    float sc = g2[c] / sqrtf(var + 1e-5f);
    float sh = b2[c] - mean * sc;
    float v = C2[((size_t)n * 25 + sp) * 128 + c] * sc + sh;
    acc += v * r[j];
  }
  __shared__ float red[256];
  red[t] = acc;
  __syncthreads();
  for (int s = 128; s > 0; s >>= 1) {
    if (t < s) red[t] += red[t + s];
    __syncthreads();
  }
  if (t == 0) {
    float z = red[0] + c_in[0];
    out[n] = 1.f / (1.f + expf(-z));
  }
}

// ---------------- workspace layout (bytes) ----------------
static constexpr size_t OFF_XT   = 0;              // 115,605,504
static constexpr size_t OFF_A2   = 115605504;      // 7,372,800
static constexpr size_t OFF_C2P  = 122978304;      // 6,553,600
static constexpr size_t OFF_C2   = 129531904;      // 819,200
static constexpr size_t OFF_W1R  = 130351104;      // 2,359,296
static constexpr size_t OFF_W2S  = 132710400;      // 589,824
static constexpr size_t OFF_T4   = 133300224;      // 2,048
static constexpr size_t OFF_STATS= 133302272;      // 4,096
static constexpr size_t OFF_RA   = 133306368;      // 13,056
static constexpr size_t OFF_RB   = 133319424;      // 13,056
static constexpr size_t OFF_CA   = 133332480;      // 128
static constexpr size_t OFF_CB   = 133332608;      // 128

extern "C" void kernel_launch(void* const* d_in, const int* in_sizes, int n_in,
                              void* d_out, int out_size, void* d_ws, size_t ws_size,
                              hipStream_t stream) {
  const float* x   = (const float*)d_in[0];
  const float* w1  = (const float*)d_in[1];
  const float* g1  = (const float*)d_in[3];
  const float* bb1 = (const float*)d_in[4];
  const float* w2  = (const float*)d_in[5];
  const float* g2  = (const float*)d_in[7];
  const float* bb2 = (const float*)d_in[8];

  char* ws = (char*)d_ws;
  unsigned short* xT  = (unsigned short*)(ws + OFF_XT);
  unsigned short* A2  = (unsigned short*)(ws + OFF_A2);
  float*          C2P = (float*)(ws + OFF_C2P);
  float*          C2  = (float*)(ws + OFF_C2);
  unsigned short* W1r = (unsigned short*)(ws + OFF_W1R);
  unsigned short* W2s = (unsigned short*)(ws + OFF_W2S);
  float*          T4  = (float*)(ws + OFF_T4);
  float* SUM1 = (float*)(ws + OFF_STATS);
  float* SQ1  = (float*)(ws + OFF_STATS + 1024);
  float* SUM2 = (float*)(ws + OFF_STATS + 2048);
  float* SQ2  = (float*)(ws + OFF_STATS + 3072);
  float* RA   = (float*)(ws + OFF_RA);
  float* RB   = (float*)(ws + OFF_RB);
  float* CA   = (float*)(ws + OFF_CA);
  float* CB   = (float*)(ws + OFF_CB);

  hipMemsetAsync(ws + OFF_STATS, 0, 4096, stream);
  hipMemsetAsync(A2, 0, 7372800, stream);    // pad entries never written by gemm1

  cast1<<<512, 256, 0, stream>>>(w1, W1r);
  transpose_x<<<dim3(8, 42, 64), 256, 0, stream>>>(x, xT);

  // conv1 GEMM fused: BK=128 per barrier; stats + direct A2 emission
  gemm1_fused<<<dim3(196, 4), 256, 0, stream>>>(xT, W1r, A2, SUM1, SQ1);

  // fold BN1 affine into conv2 weights + 4-class shift table
  prep2<<<640, 256, 0, stream>>>(w2, g1, bb1, SUM1, SQ1, W2s, T4);

  // conv2 as GEMM: 64x64 tiles, BK=96, K-split 8 -> 400 blocks
  gemm_bf16<3><<<dim3(25, 2, 8), 256, 0, stream>>>(A2, W2s, C2P, 1600, 128, 2304, 288);
  reduce2_k<<<100, 128, 0, stream>>>(C2P, T4, C2, SUM2, SQ2);

  // MLP composition
  mlp_head<<<1, 256, 0, stream>>>(
      (const float*)d_in[31], (const float*)d_in[32],
      (const float*)d_in[29], (const float*)d_in[30],
      (const float*)d_in[27], (const float*)d_in[28],
      (const float*)d_in[25], (const float*)d_in[26],
      (const float*)d_in[23], (const float*)d_in[24],
      (const float*)d_in[21], (const float*)d_in[22],
      (const float*)d_in[19], (const float*)d_in[20],
      (const float*)d_in[17], (const float*)d_in[18],
      RA, CA);
  mlp_stage<<<16, 256, 0, stream>>>((const float*)d_in[15], (const float*)d_in[16],
                                    RA, CA, RB, CB, 512, 256);
  mlp_stage<<<32, 256, 0, stream>>>((const float*)d_in[13], (const float*)d_in[14],
                                    RB, CB, RA, CA, 1024, 512);
  mlp_stage<<<64, 256, 0, stream>>>((const float*)d_in[11], (const float*)d_in[12],
                                    RA, CA, RB, CB, 2048, 1024);
  mlp_stage<<<100, 256, 0, stream>>>((const float*)d_in[9], (const float*)d_in[10],
                                     RB, CB, RA, CA, 3200, 2048);

  final_k<<<64, 256, 0, stream>>>(C2, SUM2, SQ2, g2, bb2, RA, CA, (float*)d_out);
}

// Round 7
// 788.475 us; speedup vs baseline: 1.0995x; 1.0559x over previous
//
#include <hip/hip_runtime.h>
#include <cstdint>
#include <cstddef>

typedef short bf16x8 __attribute__((ext_vector_type(8)));
typedef float f32x4 __attribute__((ext_vector_type(4)));

__device__ __forceinline__ unsigned short f2bf(float f) {
  union { float f; unsigned u; } v; v.f = f;
  unsigned r = v.u + 0x7fffu + ((v.u >> 16) & 1u);
  return (unsigned short)(r >> 16);
}

// async global->LDS 16B per lane; LDS dest = wave-uniform base + lane*16
#define GLOAD_LDS16(gp, lp)                                            \
  __builtin_amdgcn_global_load_lds(                                    \
      (const __attribute__((address_space(1))) void*)(const void*)(gp),\
      (__attribute__((address_space(3))) void*)(void*)(lp), 16, 0, 0)

// ---------------- init: cast+reorder w1, zero A2, zero stats ---------------
// grid 2313: [0,512) cast w1 -> W1r[co][(kh*3+kw)*512+ci]; [512,2312) zero A2;
// 2312: zero stats.
__global__ __launch_bounds__(256) void init_k(const float* __restrict__ w1,
                                              unsigned short* __restrict__ W1r,
                                              unsigned short* __restrict__ A2,
                                              float* __restrict__ stats) {
  int bid = blockIdx.x, t = threadIdx.x;
  if (bid < 512) {
    int idx = bid * 256 + t;                  // co*512+ci
    int co = idx >> 9, ci = idx & 511;
    const float* src = w1 + (size_t)idx * 9;
#pragma unroll
    for (int r = 0; r < 9; ++r)
      W1r[(size_t)co * 4608 + r * 512 + ci] = f2bf(src[r]);
  } else if (bid < 2312) {
    int idx = (bid - 512) * 256 + t;          // < 460800 chunks of 16B
    ((uint4*)A2)[idx] = make_uint4(0, 0, 0, 0);
  } else {
    ((float4*)stats)[t] = make_float4(0.f, 0.f, 0.f, 0.f);  // 4096 B
  }
}

// ---------------- transpose x (NCHW fp32) -> xT[img][ih+1][iw+1][ci] bf16 --
__global__ __launch_bounds__(256) void transpose_x(const float* __restrict__ x,
                                                   unsigned short* __restrict__ xT) {
  __shared__ float lds[64 * 41];
  int t = threadIdx.x;
  int cc = blockIdx.x, ihp = blockIdx.y, img = blockIdx.z;
  int ih = ihp - 1;
  bool rowvalid = (unsigned)ih < 40u;
  if (rowvalid) {
    for (int idx = t; idx < 640; idx += 256) {   // 64 ci x 10 float4
      int row = idx / 10, q = idx - row * 10;
      float4 v = *(const float4*)(x + (((size_t)img * 512 + cc * 64 + row) * 40 + ih) * 40 + q * 4);
      float* d = lds + row * 41 + q * 4;
      d[0] = v.x; d[1] = v.y; d[2] = v.z; d[3] = v.w;
    }
  }
  __syncthreads();
  for (int idx = t; idx < 672; idx += 256) {     // 42 iwp x 16 ushort4
    int iwp = idx >> 4, u = idx & 15;
    int iw = iwp - 1;
    bool ok = rowvalid && (unsigned)iw < 40u;
    ushort4 o;
    unsigned short vv[4];
#pragma unroll
    for (int j = 0; j < 4; ++j)
      vv[j] = ok ? f2bf(lds[(u * 4 + j) * 41 + iw]) : (unsigned short)0;
    o.x = vv[0]; o.y = vv[1]; o.z = vv[2]; o.w = vv[3];
    *(ushort4*)(xT + (((size_t)img * 42 + ihp) * 42 + iwp) * 512 + cc * 64 + u * 4) = o;
  }
}

// ---------------- fused conv1 GEMM ------------------------------------------
// A via swizzled LDS (BK=128, 4 sub-buffers of 64x32; chunk for (row,piece p)
// is row*4 + (p ^ ((row>>1)&3)) -> 2-way bank spread, conflict-free).
// B (W1r, 2.3 MB, L2-hot) loaded DIRECTLY global->VGPR, no LDS, no barrier.
// Epilogue: BN1 stats + scatter C directly as A2 (conv2 im2col bijection).
__global__ __launch_bounds__(256) void gemm1_fused(const unsigned short* __restrict__ xT,
                                                   const unsigned short* __restrict__ W1r,
                                                   unsigned short* __restrict__ A2,
                                                   float* __restrict__ SUM1,
                                                   float* __restrict__ SQ1) {
  __shared__ __align__(16) unsigned short As[4 * 64 * 32];   // 16 KB
  int t = threadIdx.x;
  int m0 = blockIdx.x * 64;
  int n0 = blockIdx.y * 64;
  // A staging: thread t stages row R = t>>2, swizzled piece p
  int R = t >> 2;
  int p = (t & 3) ^ ((R >> 1) & 3);
  int arow = m0 + R;
  int img_s = arow / 196, sp_s = arow - img_s * 196;
  int oh_s = sp_s / 14, ow_s = sp_s - oh_s * 14;
  const unsigned short* Abase =
      xT + (((size_t)img_s * 42 + 3 * oh_s) * 42 + 3 * ow_s) * 512 + p * 8;
  int q = (t & 63) >> 4, mr = t & 15;
  int wm = ((t >> 6) & 1) * 32;
  int wn = (t >> 7) * 32;
  const unsigned short* Brow = W1r + (size_t)(n0 + wn + mr) * 4608 + q * 8;
  f32x4 acc[2][2] = {};

  for (int kc = 0; kc < 36; ++kc) {
    int r = kc >> 2;                       // tap 0..8 (wave-uniform)
    int kh = (r >= 6) ? 2 : (r >= 3 ? 1 : 0);
    int kw = r - 3 * kh;
    int aoff = (kh * 42 + kw) * 512 + (kc & 3) * 128;
    __syncthreads();
#pragma unroll
    for (int i = 0; i < 4; ++i)
      GLOAD_LDS16(Abase + aoff + i * 32, As + (i * 256 + t) * 8);
    __syncthreads();
#pragma unroll
    for (int ks = 0; ks < 4; ++ks) {
      bf16x8 af[2], bfr[2];
#pragma unroll
      for (int s = 0; s < 2; ++s) {
        int Rr = wm + s * 16 + mr;
        int ch = Rr * 4 + (q ^ ((Rr >> 1) & 3));
        af[s] = *((const bf16x8*)(As + ks * 2048 + ch * 8));
      }
#pragma unroll
      for (int nt = 0; nt < 2; ++nt)
        bfr[nt] = *((const bf16x8*)(Brow + (size_t)nt * 16 * 4608 + kc * 128 + ks * 32));
#pragma unroll
      for (int nt = 0; nt < 2; ++nt)
#pragma unroll
        for (int s = 0; s < 2; ++s)
          acc[s][nt] = __builtin_amdgcn_mfma_f32_16x16x32_bf16(af[s], bfr[nt], acc[s][nt], 0, 0, 0);
    }
  }

  // ---- BN1 stats: per-column (co) sum & sumsq over this block's 64 rows ----
#pragma unroll
  for (int nt = 0; nt < 2; ++nt) {
    float cs = 0.f, cq = 0.f;
#pragma unroll
    for (int s = 0; s < 2; ++s)
#pragma unroll
      for (int rr = 0; rr < 4; ++rr) {
        float v = acc[s][nt][rr];
        cs += v; cq += v * v;
      }
    cs += __shfl_xor(cs, 16, 64); cq += __shfl_xor(cq, 16, 64);
    cs += __shfl_xor(cs, 32, 64); cq += __shfl_xor(cq, 32, 64);
    if (q == 0) {
      int col = n0 + wn + nt * 16 + mr;
      atomicAdd(&SUM1[col], cs);
      atomicAdd(&SQ1[col], cq);
    }
  }

  // ---- scatter C-tile directly into A2 (bijection; pads pre-zeroed) ----
  // C/D layout: row = q*4 + rr (M), col = mr (N)   [m89-verified]
#pragma unroll
  for (int s = 0; s < 2; ++s)
#pragma unroll
    for (int rr = 0; rr < 4; ++rr) {
      int m = m0 + wm + s * 16 + q * 4 + rr;
      int img = m / 196, sp = m - img * 196;
      int oh1 = sp / 14, ow1 = sp - oh1 * 14;
      int oh2 = (oh1 + 1) / 3, kh2 = (oh1 + 1) - 3 * oh2;
      int ow2 = (ow1 + 1) / 3, kw2 = (ow1 + 1) - 3 * ow2;
      size_t dst = (size_t)(img * 25 + oh2 * 5 + ow2) * 2304 + (kh2 * 3 + kw2) * 256;
#pragma unroll
      for (int nt = 0; nt < 2; ++nt)
        A2[dst + n0 + wn + nt * 16 + mr] = f2bf(acc[s][nt][rr]);
    }
}

// ---------------- prep2: W2s[co][(kh*3+kw)*256+ci] = bf16(w2*sc1[ci]);
//                  T4[cls][co] = sum over valid taps of w2*sh1[ci] -----------
__global__ __launch_bounds__(256) void prep2(const float* __restrict__ w2,
                                             const float* __restrict__ g1,
                                             const float* __restrict__ b1,
                                             const float* __restrict__ SUM1,
                                             const float* __restrict__ SQ1,
                                             unsigned short* __restrict__ W2s,
                                             float* __restrict__ T4) {
  int bid = blockIdx.x, t = threadIdx.x;
  if (bid < 128) {
    int idx = bid * 256 + t;            // co*256+ci
    int co = idx >> 8, ci = idx & 255;
    float mean = SUM1[ci] * (1.f / 12544.f);
    float var = SQ1[ci] * (1.f / 12544.f) - mean * mean;
    float sc = g1[ci] * rsqrtf(var + 1e-5f);
    const float* src = w2 + (size_t)idx * 9;
#pragma unroll
    for (int r = 0; r < 9; ++r)
      W2s[(size_t)co * 2304 + r * 256 + ci] = f2bf(src[r] * sc);
  } else {
    int b2 = bid - 128;                 // < 512 : cls*128 + co
    int cls = b2 >> 7, co = b2 & 127;
    int ci = t;
    float mean = SUM1[ci] * (1.f / 12544.f);
    float var = SQ1[ci] * (1.f / 12544.f) - mean * mean;
    float sc = g1[ci] * rsqrtf(var + 1e-5f);
    float sh = b1[ci] - mean * sc;
    const float* src = w2 + ((size_t)co * 256 + ci) * 9;
    float pacc = 0.f;
#pragma unroll
    for (int r = 0; r < 9; ++r) {
      int kh = r / 3, kw = r - 3 * kh;
      bool ok = ((cls & 2) || kh > 0) && ((cls & 1) || kw > 0);
      if (ok) pacc += src[r];
    }
    pacc *= sh;
    __shared__ float red[256];
    red[t] = pacc; __syncthreads();
    for (int s = 128; s > 0; s >>= 1) {
      if (t < s) red[t] += red[t + s];
      __syncthreads();
    }
    if (t == 0) T4[cls * 128 + co] = red[0];
  }
}

// ---------------- bf16 GEMM 64x64, K-split, BKS 32-wide sub-buffers ---------
template <int BKS>
__global__ __launch_bounds__(256) void gemm_bf16(const unsigned short* __restrict__ A,
                                                 const unsigned short* __restrict__ B,
                                                 float* __restrict__ Cp,
                                                 int M, int N, int K, int k_chunk) {
  __shared__ __align__(16) unsigned short As[BKS * 64 * 32];
  __shared__ __align__(16) unsigned short Bs[BKS * 64 * 32];
  int m0 = blockIdx.x * 64;
  int n0 = blockIdx.y * 64;
  Cp += (size_t)blockIdx.z * M * N;
  int k_begin = blockIdx.z * k_chunk;
  int t = threadIdx.x;
  const unsigned short* Abase = A + (size_t)(m0 + (t >> 2)) * K + (t & 3) * 8;
  const unsigned short* Bbase = B + (size_t)(n0 + (t >> 2)) * K + (t & 3) * 8;
  int q = (t & 63) >> 4, mr = t & 15;
  int wm = ((t >> 6) & 1) * 32;
  int wn = (t >> 7) * 32;
  f32x4 acc[2][2] = {};

  for (int k0 = k_begin; k0 < k_begin + k_chunk; k0 += 32 * BKS) {
    __syncthreads();
#pragma unroll
    for (int i = 0; i < BKS; ++i) {
      GLOAD_LDS16(Abase + k0 + i * 32, As + (i * 256 + t) * 8);
      GLOAD_LDS16(Bbase + k0 + i * 32, Bs + (i * 256 + t) * 8);
    }
    __syncthreads();
#pragma unroll
    for (int ks = 0; ks < BKS; ++ks) {
      bf16x8 af[2], bfr[2];
#pragma unroll
      for (int s = 0; s < 2; ++s)
        af[s] = *((const bf16x8*)(As + ks * 2048 + (wm + s * 16 + mr) * 32 + q * 8));
#pragma unroll
      for (int nt = 0; nt < 2; ++nt)
        bfr[nt] = *((const bf16x8*)(Bs + ks * 2048 + (wn + nt * 16 + mr) * 32 + q * 8));
#pragma unroll
      for (int nt = 0; nt < 2; ++nt)
#pragma unroll
        for (int s = 0; s < 2; ++s)
          acc[s][nt] = __builtin_amdgcn_mfma_f32_16x16x32_bf16(af[s], bfr[nt], acc[s][nt], 0, 0, 0);
    }
  }
#pragma unroll
  for (int s = 0; s < 2; ++s)
#pragma unroll
    for (int nt = 0; nt < 2; ++nt)
#pragma unroll
      for (int r = 0; r < 4; ++r)
        Cp[(size_t)(m0 + wm + s * 16 + q * 4 + r) * N + n0 + wn + nt * 16 + mr] = acc[s][nt][r];
}

// ---------------- reduce conv2 partials + shift table + BN2 stats ----------
__global__ void reduce2_k(const float* __restrict__ C2P, const float* __restrict__ T4,
                          float* __restrict__ C2, float* __restrict__ SUM2,
                          float* __restrict__ SQ2) {
  int c = threadIdx.x;            // 128
  int r0 = blockIdx.x * 16;       // 100 blocks
  float s = 0.f, s2 = 0.f;
  for (int r = 0; r < 16; ++r) {
    int m = r0 + r, sp = m % 25;
    int oh = sp / 5, ow = sp - oh * 5;
    int cls = ((oh > 0) ? 2 : 0) | ((ow > 0) ? 1 : 0);
    size_t off = (size_t)m * 128 + c;
    float v = T4[cls * 128 + c];
#pragma unroll
    for (int k = 0; k < 8; ++k) v += C2P[(size_t)k * 204800 + off];
    C2[off] = v;
    s += v; s2 += v * v;
  }
  atomicAdd(&SUM2[c], s);
  atomicAdd(&SQ2[c], s2);
}

// ---------------- MLP composition: w14..w5 in ONE 1024-thread block --------
__global__ __launch_bounds__(1024) void mlp_head1024(
    const float* w14, const float* b14, const float* w13, const float* b13,
    const float* w12, const float* b12, const float* w11, const float* b11,
    const float* w10, const float* b10, const float* w9,  const float* b9,
    const float* w8,  const float* b8,  const float* w7,  const float* b7,
    const float* w6,  const float* b6,  const float* w5,  const float* b5,
    float* __restrict__ r_out, float* __restrict__ c_out) {
  __shared__ float ra[1024], rb[1024];
  __shared__ float csv;
  int t = threadIdx.x;
  if (t < 2) ra[t] = w14[t];
  if (t == 0) csv = b14[0];
  __syncthreads();
  const float* Ws[9] = {w13, w12, w11, w10, w9, w8, w7, w6, w5};
  const float* Bs[9] = {b13, b12, b11, b10, b9, b8, b7, b6, b5};
  const int fouts[9] = {2, 4, 8, 16, 32, 64, 128, 256, 512};
  float* cur = ra; float* nxt = rb;
  for (int s = 0; s < 9; ++s) {
    int fo = fouts[s], fi = fo * 2;
    // bias fold: wave 0 computes dot(cur[0:fo], Bs[s])
    if (t < 64) {
      float pd = 0.f;
      for (int i = t; i < fo; i += 64) pd += cur[i] * Bs[s][i];
#pragma unroll
      for (int off = 32; off > 0; off >>= 1) pd += __shfl_down(pd, off, 64);
      if (t == 0) csv += pd;
    }
    if (t < fi) {
      float a = 0.f;
      const float* W = Ws[s];
      for (int i = 0; i < fo; ++i) a += cur[i] * W[i * fi + t];
      nxt[t] = a;
    }
    __syncthreads();
    float* tmp = cur; cur = nxt; nxt = tmp;
  }
  r_out[t] = cur[t];               // len 1024
  if (t == 0) c_out[0] = csv;
}

__global__ void mlp_stage(const float* __restrict__ W, const float* __restrict__ bt,
                          const float* __restrict__ r_in, const float* __restrict__ c_in,
                          float* __restrict__ r_out, float* __restrict__ c_out,
                          int fin, int fout) {
  __shared__ float red[256];
  int t = threadIdx.x;
  int jl = t & 31, ig = t >> 5;
  int j = blockIdx.x * 32 + jl;
  int chunk = fout >> 3;
  int i0 = ig * chunk;
  float acc = 0.f;
  for (int i = i0; i < i0 + chunk; ++i)
    acc += r_in[i] * W[(size_t)i * fin + j];
  red[t] = acc;
  __syncthreads();
  if (ig == 0) {
    float s = 0.f;
#pragma unroll
    for (int u = 0; u < 8; ++u) s += red[u * 32 + jl];
    r_out[j] = s;
  }
  if (blockIdx.x == 0) {
    __syncthreads();
    float p = 0.f;
    for (int i = t; i < fout; i += 256) p += r_in[i] * bt[i];
    red[t] = p;
    __syncthreads();
    for (int s = 128; s > 0; s >>= 1) {
      if (t < s) red[t] += red[t + s];
      __syncthreads();
    }
    if (t == 0) c_out[0] = red[0] + c_in[0];
  }
}

// ---------------- final: BN2 (inline) + dot + sigmoid ----------------
__global__ void final_k(const float* __restrict__ C2, const float* __restrict__ SUM2,
                        const float* __restrict__ SQ2, const float* __restrict__ g2,
                        const float* __restrict__ b2, const float* __restrict__ r,
                        const float* __restrict__ c_in, float* __restrict__ out) {
  int n = blockIdx.x;       // 64
  int t = threadIdx.x;      // 256
  float acc = 0.f;
  for (int j = t; j < 3200; j += 256) {
    int c = j / 25, sp = j - c * 25;
    float mean = SUM2[c] * (1.f / 1600.f);
    float var = SQ2[c] * (1.f / 1600.f) - mean * mean;
    float sc = g2[c] / sqrtf(var + 1e-5f);
    float sh = b2[c] - mean * sc;
    float v = C2[((size_t)n * 25 + sp) * 128 + c] * sc + sh;
    acc += v * r[j];
  }
  __shared__ float red[256];
  red[t] = acc;
  __syncthreads();
  for (int s = 128; s > 0; s >>= 1) {
    if (t < s) red[t] += red[t + s];
    __syncthreads();
  }
  if (t == 0) {
    float z = red[0] + c_in[0];
    out[n] = 1.f / (1.f + expf(-z));
  }
}

// ---------------- workspace layout (bytes) ----------------
static constexpr size_t OFF_XT   = 0;              // 115,605,504
static constexpr size_t OFF_A2   = 115605504;      // 7,372,800
static constexpr size_t OFF_C2P  = 122978304;      // 6,553,600
static constexpr size_t OFF_C2   = 129531904;      // 819,200
static constexpr size_t OFF_W1R  = 130351104;      // 2,359,296
static constexpr size_t OFF_W2S  = 132710400;      // 589,824
static constexpr size_t OFF_T4   = 133300224;      // 2,048
static constexpr size_t OFF_STATS= 133302272;      // 4,096
static constexpr size_t OFF_RA   = 133306368;      // 13,056
static constexpr size_t OFF_RB   = 133319424;      // 13,056
static constexpr size_t OFF_CA   = 133332480;      // 128
static constexpr size_t OFF_CB   = 133332608;      // 128

extern "C" void kernel_launch(void* const* d_in, const int* in_sizes, int n_in,
                              void* d_out, int out_size, void* d_ws, size_t ws_size,
                              hipStream_t stream) {
  const float* x   = (const float*)d_in[0];
  const float* w1  = (const float*)d_in[1];
  const float* g1  = (const float*)d_in[3];
  const float* bb1 = (const float*)d_in[4];
  const float* w2  = (const float*)d_in[5];
  const float* g2  = (const float*)d_in[7];
  const float* bb2 = (const float*)d_in[8];

  char* ws = (char*)d_ws;
  unsigned short* xT  = (unsigned short*)(ws + OFF_XT);
  unsigned short* A2  = (unsigned short*)(ws + OFF_A2);
  float*          C2P = (float*)(ws + OFF_C2P);
  float*          C2  = (float*)(ws + OFF_C2);
  unsigned short* W1r = (unsigned short*)(ws + OFF_W1R);
  unsigned short* W2s = (unsigned short*)(ws + OFF_W2S);
  float*          T4  = (float*)(ws + OFF_T4);
  float* SUM1 = (float*)(ws + OFF_STATS);
  float* SQ1  = (float*)(ws + OFF_STATS + 1024);
  float* SUM2 = (float*)(ws + OFF_STATS + 2048);
  float* SQ2  = (float*)(ws + OFF_STATS + 3072);
  float* RA   = (float*)(ws + OFF_RA);
  float* RB   = (float*)(ws + OFF_RB);
  float* CA   = (float*)(ws + OFF_CA);
  float* CB   = (float*)(ws + OFF_CB);

  // one kernel: w1 cast/reorder + A2 zero + stats zero
  init_k<<<2313, 256, 0, stream>>>(w1, W1r, A2, (float*)(ws + OFF_STATS));

  transpose_x<<<dim3(8, 42, 64), 256, 0, stream>>>(x, xT);

  // conv1 GEMM fused: swizzled-A LDS, direct-global B, stats + A2 emission
  gemm1_fused<<<dim3(196, 4), 256, 0, stream>>>(xT, W1r, A2, SUM1, SQ1);

  // fold BN1 affine into conv2 weights + 4-class shift table
  prep2<<<640, 256, 0, stream>>>(w2, g1, bb1, SUM1, SQ1, W2s, T4);

  // conv2 as GEMM: 64x64 tiles, BK=96, K-split 8 -> 400 blocks
  gemm_bf16<3><<<dim3(25, 2, 8), 256, 0, stream>>>(A2, W2s, C2P, 1600, 128, 2304, 288);
  reduce2_k<<<100, 128, 0, stream>>>(C2P, T4, C2, SUM2, SQ2);

  // MLP composition: w14..w5 in one block, then w4, w3 multi-block
  mlp_head1024<<<1, 1024, 0, stream>>>(
      (const float*)d_in[31], (const float*)d_in[32],
      (const float*)d_in[29], (const float*)d_in[30],
      (const float*)d_in[27], (const float*)d_in[28],
      (const float*)d_in[25], (const float*)d_in[26],
      (const float*)d_in[23], (const float*)d_in[24],
      (const float*)d_in[21], (const float*)d_in[22],
      (const float*)d_in[19], (const float*)d_in[20],
      (const float*)d_in[17], (const float*)d_in[18],
      (const float*)d_in[15], (const float*)d_in[16],
      (const float*)d_in[13], (const float*)d_in[14],
      RB, CB);
  mlp_stage<<<64, 256, 0, stream>>>((const float*)d_in[11], (const float*)d_in[12],
                                    RB, CB, RA, CA, 2048, 1024);   // w4
  mlp_stage<<<100, 256, 0, stream>>>((const float*)d_in[9], (const float*)d_in[10],
                                     RA, CA, RB, CB, 3200, 2048);  // w3

  final_k<<<64, 256, 0, stream>>>(C2, SUM2, SQ2, g2, bb2, RB, CB, (float*)d_out);
}